// Round 12
// baseline (324.270 us; speedup 1.0000x reference)
//
#include <hip/hip_runtime.h>
#include <hip/hip_fp16.h>

// R23: MEASUREMENT ROUND. R22 structure unchanged except gather is split
// into 3 dispatches of ~261 buckets (~33us each). Rationale: non-gather
// budget (192us) has resisted 5 rounds of blind helper rewrites; place and
// dcxw have NEVER appeared in top-5 (saturated by 16 iterations of the
// slowest kernel). With gather thirds at ~33us, any helper >=36us MUST
// surface as top row WITH its counters. Cost: 2 extra dispatch boundaries
// (~+10us predicted).
//
// code = (dst_local<<18) | vsrc; dst_local = 2*(d&127)+type; vsrc = 2*s+type
// vnode = 2*node+type; bucket = vnode>>8 = d>>7 (type-free).

#define SLICES 256
#define BSZ    256            // vnodes per bucket (=128 node pairs)
#define NB_MAX 800
#define CAP2   9216           // words reserved per bucket (mult of 4)
#define PCH    4096           // place: edges per chunk (512 thr x 8)
#define LDSPAD 33
#define FXS    65536.0f
#define FXSI   (1.0f / 65536.0f)

// ---------------- 0. init: zero goff + transpose W into workspace ------------
__global__ __launch_bounds__(512)
void init_kernel(const float* __restrict__ Wn, const float* __restrict__ Ws,
                 int* __restrict__ goff, float* __restrict__ wtn,
                 float* __restrict__ wts, int nb) {
    const int t = threadIdx.x;
    for (int b = t; b < nb; b += 512) goff[b] = 0;
    for (int i = t; i < 64 * 32; i += 512) {
        int k = i >> 5, h = i & 31;
        wtn[h * 64 + k] = Wn[i];
        wts[h * 64 + k] = Ws[i];
    }
}

// ---------------- 1. place: 2-pass LDS radix, wave-shfl scan ------------------
__global__ __launch_bounds__(512)
void place_kernel(const int* __restrict__ ei_n, const int* __restrict__ ei_s,
                  int* __restrict__ goff, unsigned int* __restrict__ codes,
                  int En, int Es, int nb) {
    __shared__ unsigned stg[PCH];        // 16 KB
    __shared__ unsigned stg2[PCH];       // 16 KB global position per element
    __shared__ int histT[NB_MAX];        // slice-total hist
    __shared__ int cur[NB_MAX];          // running global cursors
    __shared__ int histC[NB_MAX];        // per-chunk hist
    __shared__ int baseC[NB_MAX];        // per-chunk stage base
    __shared__ int gbC[NB_MAX];          // per-chunk cursor snapshot
    __shared__ int wsum[8];
    const int t = threadIdx.x;
    const int wid = t >> 6, lane = t & 63;
    const int type = blockIdx.y;
    const int* __restrict__ ei = type ? ei_s : ei_n;
    const int E = type ? Es : En;
    int per = ((E + SLICES - 1) / SLICES + 7) & ~7;
    const int e0 = blockIdx.x * per;
    const int e1 = min(e0 + per, E);

    for (int b = t; b < nb; b += 512) histT[b] = 0;
    __syncthreads();

    // ---- pass A: slice-total histogram (dst stream only, no inner barriers)
    for (int c0 = e0; c0 < e1; c0 += PCH) {
        const int i = c0 + t * 8;
        int nv = e1 - i; nv = nv < 0 ? 0 : (nv > 8 ? 8 : nv);
        if (nv == 8) {
            int4 dA = *(const int4*)(ei + E + i), dB = *(const int4*)(ei + E + i + 4);
            atomicAdd(&histT[dA.x >> 7], 1);
            atomicAdd(&histT[dA.y >> 7], 1);
            atomicAdd(&histT[dA.z >> 7], 1);
            atomicAdd(&histT[dA.w >> 7], 1);
            atomicAdd(&histT[dB.x >> 7], 1);
            atomicAdd(&histT[dB.y >> 7], 1);
            atomicAdd(&histT[dB.z >> 7], 1);
            atomicAdd(&histT[dB.w >> 7], 1);
        } else {
            for (int j = 0; j < nv; ++j) atomicAdd(&histT[ei[E + i + j] >> 7], 1);
        }
    }
    __syncthreads();

    // ---- single global reservation per block
    for (int b = t; b < nb; b += 512) {
        int c = histT[b];
        cur[b] = b * CAP2 + (c ? atomicAdd(&goff[b], c) : 0);
    }
    for (int b = t; b < nb; b += 512) histC[b] = 0;
    __syncthreads();

    // ---- pass B: per-chunk rank + wave-scan + stage + coalesced flush
    for (int c0 = e0; c0 < e1; c0 += PCH) {
        const int i = c0 + t * 8;
        int nv = e1 - i; nv = nv < 0 ? 0 : (nv > 8 ? 8 : nv);
        unsigned cd[8]; int bb[8], rk[8];
        if (nv == 8) {
            int4 sA = *(const int4*)(ei + i),     sB = *(const int4*)(ei + i + 4);
            int4 dA = *(const int4*)(ei + E + i), dB = *(const int4*)(ei + E + i + 4);
            int ss[8] = {sA.x, sA.y, sA.z, sA.w, sB.x, sB.y, sB.z, sB.w};
            int dd[8] = {dA.x, dA.y, dA.z, dA.w, dB.x, dB.y, dB.z, dB.w};
#pragma unroll
            for (int j = 0; j < 8; ++j) {
                bb[j] = dd[j] >> 7;
                cd[j] = ((unsigned)(2 * (dd[j] & 127) + type) << 18)
                      | (unsigned)(2 * ss[j] + type);
            }
        } else {
            for (int j = 0; j < nv; ++j) {
                int sv = ei[i + j], dv = ei[E + i + j];
                bb[j] = dv >> 7;
                cd[j] = ((unsigned)(2 * (dv & 127) + type) << 18)
                      | (unsigned)(2 * sv + type);
            }
        }
#pragma unroll
        for (int j = 0; j < 8; ++j)
            if (j < nv) rk[j] = atomicAdd(&histC[bb[j]], 1);
        __syncthreads();                               // histC final

        // wave-structured exclusive scan: wave w covers [128w, 128w+128)
        const int i0 = wid * 128 + lane, i1 = i0 + 64;
        int v0 = (i0 < nb) ? histC[i0] : 0;
        int v1 = (i1 < nb) ? histC[i1] : 0;
        int x0 = v0;
#pragma unroll
        for (int o = 1; o < 64; o <<= 1) { int n = __shfl_up(x0, o, 64); if (lane >= o) x0 += n; }
        int tot0 = __shfl(x0, 63, 64);
        int x1 = v1;
#pragma unroll
        for (int o = 1; o < 64; o <<= 1) { int n = __shfl_up(x1, o, 64); if (lane >= o) x1 += n; }
        int tot1 = __shfl(x1, 63, 64);
        if (lane == 0) wsum[wid] = tot0 + tot1;
        // cursor snapshot + advance (each b owned by one thread)
        for (int b = t; b < nb; b += 512) {
            int c = histC[b], g = cur[b];
            gbC[b] = g;
            cur[b] = g + c;
        }
        __syncthreads();                               // wsum, gbC ready
        int woff = 0;
#pragma unroll
        for (int k = 0; k < 8; ++k) woff += (k < wid) ? wsum[k] : 0;
        if (i0 < nb) baseC[i0] = woff + (x0 - v0);
        if (i1 < nb) baseC[i1] = woff + tot0 + (x1 - v1);
        __syncthreads();                               // baseC ready

        // dense LDS scatter + precomputed global position
#pragma unroll
        for (int j = 0; j < 8; ++j)
            if (j < nv) {
                int p = baseC[bb[j]] + rk[j];
                stg[p] = cd[j];
                stg2[p] = (unsigned)(gbC[bb[j]] + rk[j]);
            }
        __syncthreads();                               // stage ready

        // coalesced run-ordered flush + zero histC for next chunk
        const int tot = min(PCH, e1 - c0);
        for (int j = t; j < tot; j += 512)
            codes[stg2[j]] = stg[j];
        for (int b = t; b < nb; b += 512) histC[b] = 0;
        __syncthreads();
    }
}

// ---------------- 2. dcxw: 2 buckets/block, thread=node, global-W^T xw --------
// block B covers buckets 2B,2B+1 = vnodes [512B,512B+512) = nodes [256B,256B+256)
__global__ __launch_bounds__(256)
void dcxw_kernel(const unsigned int* __restrict__ codes, const int* __restrict__ goff,
                 const float* __restrict__ x,
                 const float* __restrict__ wtn, const float* __restrict__ wts,
                 int* __restrict__ cnt, __half2* __restrict__ xws, int N, int M, int nb) {
    __shared__ int dcnt[512];
    const int t = threadIdx.x;
    dcnt[t] = 0;
    dcnt[t + 256] = 0;
    __syncthreads();

    for (int bb = 0; bb < 2; ++bb) {
        const int bidx = 2 * blockIdx.x + bb;
        if (bidx >= nb) break;
        const int off = bb << 8;
        const int base = bidx * CAP2;
        const int end = base + goff[bidx];
        const int t0 = base + ((end - base) & ~3);
        for (int e = base + t * 4; e < t0; e += 256 * 4) {
            uint4 c = *(const uint4*)(codes + e);
            atomicAdd(&dcnt[off + (c.x >> 18)], 1);
            atomicAdd(&dcnt[off + (c.y >> 18)], 1);
            atomicAdd(&dcnt[off + (c.z >> 18)], 1);
            atomicAdd(&dcnt[off + (c.w >> 18)], 1);
        }
        if (t < end - t0) atomicAdd(&dcnt[off + (codes[t0 + t] >> 18)], 1);
    }
    __syncthreads();

    const int v0 = blockIdx.x * 512 + t;
    if (v0 < M) cnt[v0] = dcnt[t];
    const int v1 = v0 + 256;
    if (v1 < M) cnt[v1] = dcnt[t + 256];

    const int node = blockIdx.x * 256 + t;
    if (node >= N) return;

    float xr[64];
    const float4* x4 = (const float4*)(x + (size_t)node * 64);
#pragma unroll
    for (int q = 0; q < 16; ++q) {
        float4 v = x4[q];
        xr[4 * q] = v.x; xr[4 * q + 1] = v.y; xr[4 * q + 2] = v.z; xr[4 * q + 3] = v.w;
    }
    float dn = rsqrtf((float)dcnt[2 * t] + 1.0f);
    float ds = rsqrtf((float)dcnt[2 * t + 1] + 1.0f);

    const float4* wn4 = (const float4*)wtn;   // wtn[h*64+k] -> wn4[h*16+q]
    const float4* ws4 = (const float4*)wts;

    unsigned pn[16], ps[16];
#pragma unroll
    for (int s2 = 0; s2 < 16; ++s2) {
        float a0n = 0.f, a1n = 0.f, a0s = 0.f, a1s = 0.f;
#pragma unroll
        for (int q = 0; q < 16; ++q) {
            // wave-uniform addresses -> scalar / L1-broadcast loads
            float4 w0n = wn4[(2 * s2) * 16 + q];
            float4 w1n = wn4[(2 * s2 + 1) * 16 + q];
            float4 w0s = ws4[(2 * s2) * 16 + q];
            float4 w1s = ws4[(2 * s2 + 1) * 16 + q];
            float x0 = xr[4 * q], x1 = xr[4 * q + 1], x2 = xr[4 * q + 2], x3 = xr[4 * q + 3];
            a0n += x0 * w0n.x + x1 * w0n.y + x2 * w0n.z + x3 * w0n.w;
            a1n += x0 * w1n.x + x1 * w1n.y + x2 * w1n.z + x3 * w1n.w;
            a0s += x0 * w0s.x + x1 * w0s.y + x2 * w0s.z + x3 * w0s.w;
            a1s += x0 * w1s.x + x1 * w1s.y + x2 * w1s.z + x3 * w1s.w;
        }
        __half2 hn = __floats2half2_rn(a0n * dn, a1n * dn);
        __half2 hs = __floats2half2_rn(a0s * ds, a1s * ds);
        pn[s2] = *(unsigned*)&hn;
        ps[s2] = *(unsigned*)&hs;
    }
    uint4* on = (uint4*)(xws + (size_t)(2 * node) * 16);
    uint4* os = (uint4*)(xws + (size_t)(2 * node + 1) * 16);
#pragma unroll
    for (int q = 0; q < 4; ++q) {
        on[q] = make_uint4(pn[4 * q], pn[4 * q + 1], pn[4 * q + 2], pn[4 * q + 3]);
        os[q] = make_uint4(ps[4 * q], ps[4 * q + 1], ps[4 * q + 2], ps[4 * q + 3]);
    }
}

// ---------------- 3. gather: bucket range [b0,b1), 1024 threads ---------------
__global__ __launch_bounds__(1024)
void gather_kernel(const unsigned int* __restrict__ codes, const int* __restrict__ goff,
                   const __half2* __restrict__ xws, const int* __restrict__ cnt,
                   const float* __restrict__ b_n, const float* __restrict__ b_s,
                   const float* __restrict__ W_lin, const float* __restrict__ b_lin,
                   float* __restrict__ out, int N, int b0) {
    __shared__ int facc[BSZ * LDSPAD];   // 33.8 KB
    for (int i = threadIdx.x; i < BSZ * LDSPAD; i += 1024) facc[i] = 0;
    __syncthreads();
    const int b = blockIdx.x + b0;
    const int base = b * CAP2;                  // multiple of 4
    const int end = base + goff[b];
    const int sl = threadIdx.x & 15;
    const int grp = threadIdx.x >> 4;           // 64 groups of 16 lanes

#define GA(cc) xws[(size_t)((cc) & 0x3FFFFu) * 16 + sl]
#define ACC_EDGE(cc, ww) do {                                                \
        float2 f_ = __half22float2(ww);                                      \
        int r_ = (int)((cc) >> 18) * LDSPAD + sl;                            \
        atomicAdd(&facc[r_],      __float2int_rn(f_.x * FXS));               \
        atomicAdd(&facc[r_ + 16], __float2int_rn(f_.y * FXS));               \
    } while (0)

    const int t0 = base + ((end - base) & ~15);
    for (int e = base + grp * 16; e < t0; e += 64 * 16) {
        uint4 c0 = *(const uint4*)(codes + e);
        uint4 c1 = *(const uint4*)(codes + e + 4);
        uint4 c2 = *(const uint4*)(codes + e + 8);
        uint4 c3 = *(const uint4*)(codes + e + 12);
        __half2 w0 = GA(c0.x), w1 = GA(c0.y), w2 = GA(c0.z), w3 = GA(c0.w);
        __half2 w4 = GA(c1.x), w5 = GA(c1.y), w6 = GA(c1.z), w7 = GA(c1.w);
        __half2 w8 = GA(c2.x), w9 = GA(c2.y), wA = GA(c2.z), wB = GA(c2.w);
        __half2 wC = GA(c3.x), wD = GA(c3.y), wE = GA(c3.z), wF = GA(c3.w);
        ACC_EDGE(c0.x, w0); ACC_EDGE(c0.y, w1); ACC_EDGE(c0.z, w2); ACC_EDGE(c0.w, w3);
        ACC_EDGE(c1.x, w4); ACC_EDGE(c1.y, w5); ACC_EDGE(c1.z, w6); ACC_EDGE(c1.w, w7);
        ACC_EDGE(c2.x, w8); ACC_EDGE(c2.y, w9); ACC_EDGE(c2.z, wA); ACC_EDGE(c2.w, wB);
        ACC_EDGE(c3.x, wC); ACC_EDGE(c3.y, wD); ACC_EDGE(c3.z, wE); ACC_EDGE(c3.w, wF);
    }
    for (int e = t0 + grp; e < end; e += 64) {
        unsigned c = codes[e];
        __half2 w = GA(c);
        ACC_EDGE(c, w);
    }
#undef ACC_EDGE
#undef GA

    __syncthreads();
    const float bn0 = b_n[2 * sl], bn1 = b_n[2 * sl + 1];
    const float bs0 = b_s[2 * sl], bs1 = b_s[2 * sl + 1];
    const float wl0 = W_lin[2 * sl], wl1 = W_lin[2 * sl + 1];
    const float bl  = b_lin[0];
    for (int p = grp; p < 128; p += 64) {
        int node = b * 128 + p;
        if (node >= N) break;
        int rn = (2 * p) * LDSPAD, rs = rn + LDSPAD;
        float anx = (float)facc[rn + sl] * FXSI, any_ = (float)facc[rn + 16 + sl] * FXSI;
        float asx = (float)facc[rs + sl] * FXSI, asy  = (float)facc[rs + 16 + sl] * FXSI;
        float2 ns = __half22float2(xws[(size_t)(2 * node) * 16 + sl]);
        float2 ss = __half22float2(xws[(size_t)(2 * node + 1) * 16 + sl]);
        float dn  = rsqrtf((float)cnt[2 * node] + 1.0f);
        float dsv = rsqrtf((float)cnt[2 * node + 1] + 1.0f);
        float h0 = (anx + ns.x) * dn + bn0 + (asx + ss.x) * dsv + bs0;
        float h1 = (any_ + ns.y) * dn + bn1 + (asy + ss.y) * dsv + bs1;
        float pr = fmaxf(h0, 0.f) * wl0 + fmaxf(h1, 0.f) * wl1;
#pragma unroll
        for (int off = 8; off > 0; off >>= 1) pr += __shfl_xor(pr, off, 16);
        if (sl == 0) out[node] = pr + bl;
    }
}

extern "C" void kernel_launch(void* const* d_in, const int* in_sizes, int n_in,
                              void* d_out, int out_size, void* d_ws, size_t ws_size,
                              hipStream_t stream) {
    const float* x     = (const float*)d_in[0];
    const int*   ei_n  = (const int*)d_in[1];
    const int*   ei_s  = (const int*)d_in[2];
    const float* W_n   = (const float*)d_in[3];
    const float* b_n   = (const float*)d_in[4];
    const float* W_s   = (const float*)d_in[5];
    const float* b_s   = (const float*)d_in[6];
    const float* W_lin = (const float*)d_in[7];
    const float* b_lin = (const float*)d_in[8];
    float* out = (float*)d_out;

    const int N  = in_sizes[0] / 64;   // 100000
    const int En = in_sizes[1] / 2;    // 3200000
    const int Es = in_sizes[2] / 2;    // 3200000
    const int M  = 2 * N;              // 200000 vnodes (vn = 2*node + type)
    const int nb = (M + BSZ - 1) / BSZ;            // 782 buckets

    // Workspace (~43 MB): goff[1024] | cnt[M] | wtn[2048] | wts[2048]
    // | codes[nb*CAP2] (16B aligned) | xws[16*M half2]
    int*   goff = (int*)d_ws;
    int*   cnt  = goff + 1024;
    float* wtn  = (float*)(cnt + M);
    float* wts  = wtn + 2048;
    uintptr_t pc = (uintptr_t)(wts + 2048);
    pc = (pc + 15) & ~(uintptr_t)15;
    unsigned int* codes = (unsigned int*)pc;
    __half2* xws = (__half2*)(codes + (size_t)nb * CAP2);

    init_kernel<<<1, 512, 0, stream>>>(W_n, W_s, goff, wtn, wts, nb);
    place_kernel<<<dim3(SLICES, 2), 512, 0, stream>>>(ei_n, ei_s, goff, codes,
                                                      En, Es, nb);
    dcxw_kernel<<<(nb + 1) / 2, 256, 0, stream>>>(codes, goff, x, wtn, wts,
                                                  cnt, xws, N, M, nb);
    // gather split into thirds: surfaces any helper >= ~36us in top-5
    const int g1 = nb / 3, g2 = 2 * nb / 3;
    gather_kernel<<<g1, 1024, 0, stream>>>(codes, goff, xws, cnt,
                                           b_n, b_s, W_lin, b_lin, out, N, 0);
    gather_kernel<<<g2 - g1, 1024, 0, stream>>>(codes, goff, xws, cnt,
                                                b_n, b_s, W_lin, b_lin, out, N, g1);
    gather_kernel<<<nb - g2, 1024, 0, stream>>>(codes, goff, xws, cnt,
                                                b_n, b_s, W_lin, b_lin, out, N, g2);
}

// Round 13
// 282.704 us; speedup vs baseline: 1.1470x; 1.1470x over previous
//
#include <hip/hip_runtime.h>
#include <hip/hip_fp16.h>

// R24: kill dcxw (MEASURED at 107us in R23: VALUBusy 6%, HBM 4.6%, Occ 16.7%
// -- latency-bound at 6 waves/CU with chained un-scalarized global W loads).
//  - dcount: own kernel, 1 bucket/block (782 blocks), streaming codes.
//  - xw: 16 threads/NODE (thread = (node, h-pair)) -> 1.6M threads, 25K
//    waves, occupancy-saturated; 4 accumulators/thread; W^T in LDS stride
//    68 (4-aligned, <=4-way conflicts); writes xws layout directly.
//  - gather back to ONE dispatch (R22's 95us version); init kernel dropped
//    (memset goff; W transpose moved into xw's LDS staging).
// Pipeline: memset -> place -> dcount -> xw -> gather.
//
// code = (dst_local<<18) | vsrc; dst_local = 2*(d&127)+type; vsrc = 2*s+type
// vnode = 2*node+type; bucket = vnode>>8 = d>>7 (type-free).

#define SLICES 256
#define BSZ    256            // vnodes per bucket (=128 node pairs)
#define NB_MAX 800
#define CAP2   9216           // words reserved per bucket (mult of 4)
#define PCH    4096           // place: edges per chunk (512 thr x 8)
#define LDSPAD 33
#define WSTR   68             // xw: W^T LDS row stride (4-aligned, odd*4)
#define FXS    65536.0f
#define FXSI   (1.0f / 65536.0f)

// ---------------- 1. place: 2-pass LDS radix, wave-shfl scan ------------------
__global__ __launch_bounds__(512)
void place_kernel(const int* __restrict__ ei_n, const int* __restrict__ ei_s,
                  int* __restrict__ goff, unsigned int* __restrict__ codes,
                  int En, int Es, int nb) {
    __shared__ unsigned stg[PCH];        // 16 KB
    __shared__ unsigned stg2[PCH];       // 16 KB global position per element
    __shared__ int histT[NB_MAX];        // slice-total hist
    __shared__ int cur[NB_MAX];          // running global cursors
    __shared__ int histC[NB_MAX];        // per-chunk hist
    __shared__ int baseC[NB_MAX];        // per-chunk stage base
    __shared__ int gbC[NB_MAX];          // per-chunk cursor snapshot
    __shared__ int wsum[8];
    const int t = threadIdx.x;
    const int wid = t >> 6, lane = t & 63;
    const int type = blockIdx.y;
    const int* __restrict__ ei = type ? ei_s : ei_n;
    const int E = type ? Es : En;
    int per = ((E + SLICES - 1) / SLICES + 7) & ~7;
    const int e0 = blockIdx.x * per;
    const int e1 = min(e0 + per, E);

    for (int b = t; b < nb; b += 512) histT[b] = 0;
    __syncthreads();

    // ---- pass A: slice-total histogram (dst stream only, no inner barriers)
    for (int c0 = e0; c0 < e1; c0 += PCH) {
        const int i = c0 + t * 8;
        int nv = e1 - i; nv = nv < 0 ? 0 : (nv > 8 ? 8 : nv);
        if (nv == 8) {
            int4 dA = *(const int4*)(ei + E + i), dB = *(const int4*)(ei + E + i + 4);
            atomicAdd(&histT[dA.x >> 7], 1);
            atomicAdd(&histT[dA.y >> 7], 1);
            atomicAdd(&histT[dA.z >> 7], 1);
            atomicAdd(&histT[dA.w >> 7], 1);
            atomicAdd(&histT[dB.x >> 7], 1);
            atomicAdd(&histT[dB.y >> 7], 1);
            atomicAdd(&histT[dB.z >> 7], 1);
            atomicAdd(&histT[dB.w >> 7], 1);
        } else {
            for (int j = 0; j < nv; ++j) atomicAdd(&histT[ei[E + i + j] >> 7], 1);
        }
    }
    __syncthreads();

    // ---- single global reservation per block
    for (int b = t; b < nb; b += 512) {
        int c = histT[b];
        cur[b] = b * CAP2 + (c ? atomicAdd(&goff[b], c) : 0);
    }
    for (int b = t; b < nb; b += 512) histC[b] = 0;
    __syncthreads();

    // ---- pass B: per-chunk rank + wave-scan + stage + coalesced flush
    for (int c0 = e0; c0 < e1; c0 += PCH) {
        const int i = c0 + t * 8;
        int nv = e1 - i; nv = nv < 0 ? 0 : (nv > 8 ? 8 : nv);
        unsigned cd[8]; int bb[8], rk[8];
        if (nv == 8) {
            int4 sA = *(const int4*)(ei + i),     sB = *(const int4*)(ei + i + 4);
            int4 dA = *(const int4*)(ei + E + i), dB = *(const int4*)(ei + E + i + 4);
            int ss[8] = {sA.x, sA.y, sA.z, sA.w, sB.x, sB.y, sB.z, sB.w};
            int dd[8] = {dA.x, dA.y, dA.z, dA.w, dB.x, dB.y, dB.z, dB.w};
#pragma unroll
            for (int j = 0; j < 8; ++j) {
                bb[j] = dd[j] >> 7;
                cd[j] = ((unsigned)(2 * (dd[j] & 127) + type) << 18)
                      | (unsigned)(2 * ss[j] + type);
            }
        } else {
            for (int j = 0; j < nv; ++j) {
                int sv = ei[i + j], dv = ei[E + i + j];
                bb[j] = dv >> 7;
                cd[j] = ((unsigned)(2 * (dv & 127) + type) << 18)
                      | (unsigned)(2 * sv + type);
            }
        }
#pragma unroll
        for (int j = 0; j < 8; ++j)
            if (j < nv) rk[j] = atomicAdd(&histC[bb[j]], 1);
        __syncthreads();                               // histC final

        // wave-structured exclusive scan: wave w covers [128w, 128w+128)
        const int i0 = wid * 128 + lane, i1 = i0 + 64;
        int v0 = (i0 < nb) ? histC[i0] : 0;
        int v1 = (i1 < nb) ? histC[i1] : 0;
        int x0 = v0;
#pragma unroll
        for (int o = 1; o < 64; o <<= 1) { int n = __shfl_up(x0, o, 64); if (lane >= o) x0 += n; }
        int tot0 = __shfl(x0, 63, 64);
        int x1 = v1;
#pragma unroll
        for (int o = 1; o < 64; o <<= 1) { int n = __shfl_up(x1, o, 64); if (lane >= o) x1 += n; }
        int tot1 = __shfl(x1, 63, 64);
        if (lane == 0) wsum[wid] = tot0 + tot1;
        // cursor snapshot + advance (each b owned by one thread)
        for (int b = t; b < nb; b += 512) {
            int c = histC[b], g = cur[b];
            gbC[b] = g;
            cur[b] = g + c;
        }
        __syncthreads();                               // wsum, gbC ready
        int woff = 0;
#pragma unroll
        for (int k = 0; k < 8; ++k) woff += (k < wid) ? wsum[k] : 0;
        if (i0 < nb) baseC[i0] = woff + (x0 - v0);
        if (i1 < nb) baseC[i1] = woff + tot0 + (x1 - v1);
        __syncthreads();                               // baseC ready

        // dense LDS scatter + precomputed global position
#pragma unroll
        for (int j = 0; j < 8; ++j)
            if (j < nv) {
                int p = baseC[bb[j]] + rk[j];
                stg[p] = cd[j];
                stg2[p] = (unsigned)(gbC[bb[j]] + rk[j]);
            }
        __syncthreads();                               // stage ready

        // coalesced run-ordered flush + zero histC for next chunk
        const int tot = min(PCH, e1 - c0);
        for (int j = t; j < tot; j += 512)
            codes[stg2[j]] = stg[j];
        for (int b = t; b < nb; b += 512) histC[b] = 0;
        __syncthreads();
    }
}

// ---------------- 2. dcount: per-bucket degree from binned codes --------------
__global__ __launch_bounds__(256)
void dcount_kernel(const unsigned int* __restrict__ codes, const int* __restrict__ goff,
                   int* __restrict__ cnt, int M) {
    __shared__ int dcnt[BSZ];
    const int t = threadIdx.x;
    dcnt[t] = 0;
    __syncthreads();
    const int b = blockIdx.x;
    const int base = b * CAP2;
    const int end = base + goff[b];
    const int t0 = base + ((end - base) & ~3);
    for (int e = base + t * 4; e < t0; e += 256 * 4) {
        uint4 c = *(const uint4*)(codes + e);
        atomicAdd(&dcnt[c.x >> 18], 1);
        atomicAdd(&dcnt[c.y >> 18], 1);
        atomicAdd(&dcnt[c.z >> 18], 1);
        atomicAdd(&dcnt[c.w >> 18], 1);
    }
    if (t < end - t0) atomicAdd(&dcnt[codes[t0 + t] >> 18], 1);
    __syncthreads();
    const int vnode = b * BSZ + t;
    if (vnode < M) cnt[vnode] = dcnt[t];
}

// ---------------- 3. xw: 16 threads/node, thread = (node, h-pair) -------------
// block = 256 threads = 16 nodes; grid = N/16 blocks (6250) -> 25K waves.
// xws[(2*node+type)*16 + sl] = half2(feat 2sl, 2sl+1) of (x@W)*rsqrt(deg+1)
__global__ __launch_bounds__(256)
void xw_kernel(const float* __restrict__ x,
               const float* __restrict__ Wn, const float* __restrict__ Ws,
               const int* __restrict__ cnt,
               __half2* __restrict__ xws, int N) {
    __shared__ float wtA[32 * WSTR];   // W_n^T: [h][k], stride 68
    __shared__ float wtB[32 * WSTR];   // W_s^T
    const int t = threadIdx.x;
    for (int i = t; i < 64 * 32; i += 256) {
        int k = i >> 5, h = i & 31;
        wtA[h * WSTR + k] = Wn[i];
        wtB[h * WSTR + k] = Ws[i];
    }
    __syncthreads();

    const int ln = t >> 4, sl = t & 15;
    const int node = blockIdx.x * 16 + ln;
    if (node >= N) return;

    const float4* x4 = (const float4*)(x + (size_t)node * 64);
    const float4* wa4 = (const float4*)&wtA[(2 * sl) * WSTR];
    const float4* wb4 = (const float4*)&wtA[(2 * sl + 1) * WSTR];
    const float4* wc4 = (const float4*)&wtB[(2 * sl) * WSTR];
    const float4* wd4 = (const float4*)&wtB[(2 * sl + 1) * WSTR];

    float a0n = 0.f, a1n = 0.f, a0s = 0.f, a1s = 0.f;
#pragma unroll
    for (int q = 0; q < 16; ++q) {
        float4 xv = x4[q];
        float4 wa = wa4[q], wb = wb4[q], wc = wc4[q], wd = wd4[q];
        a0n += xv.x * wa.x + xv.y * wa.y + xv.z * wa.z + xv.w * wa.w;
        a1n += xv.x * wb.x + xv.y * wb.y + xv.z * wb.z + xv.w * wb.w;
        a0s += xv.x * wc.x + xv.y * wc.y + xv.z * wc.z + xv.w * wc.w;
        a1s += xv.x * wd.x + xv.y * wd.y + xv.z * wd.z + xv.w * wd.w;
    }
    float dn = rsqrtf((float)cnt[2 * node] + 1.0f);
    float ds = rsqrtf((float)cnt[2 * node + 1] + 1.0f);
    xws[(size_t)(2 * node) * 16 + sl]     = __floats2half2_rn(a0n * dn, a1n * dn);
    xws[(size_t)(2 * node + 1) * 16 + sl] = __floats2half2_rn(a0s * ds, a1s * ds);
}

// ---------------- 4. gather: 1024 threads, fixed-point LDS acc + epilogue -----
__global__ __launch_bounds__(1024)
void gather_kernel(const unsigned int* __restrict__ codes, const int* __restrict__ goff,
                   const __half2* __restrict__ xws, const int* __restrict__ cnt,
                   const float* __restrict__ b_n, const float* __restrict__ b_s,
                   const float* __restrict__ W_lin, const float* __restrict__ b_lin,
                   float* __restrict__ out, int N) {
    __shared__ int facc[BSZ * LDSPAD];   // 33.8 KB
    for (int i = threadIdx.x; i < BSZ * LDSPAD; i += 1024) facc[i] = 0;
    __syncthreads();
    const int b = blockIdx.x;
    const int base = b * CAP2;                  // multiple of 4
    const int end = base + goff[b];
    const int sl = threadIdx.x & 15;
    const int grp = threadIdx.x >> 4;           // 64 groups of 16 lanes

#define GA(cc) xws[(size_t)((cc) & 0x3FFFFu) * 16 + sl]
#define ACC_EDGE(cc, ww) do {                                                \
        float2 f_ = __half22float2(ww);                                      \
        int r_ = (int)((cc) >> 18) * LDSPAD + sl;                            \
        atomicAdd(&facc[r_],      __float2int_rn(f_.x * FXS));               \
        atomicAdd(&facc[r_ + 16], __float2int_rn(f_.y * FXS));               \
    } while (0)

    const int t0 = base + ((end - base) & ~15);
    for (int e = base + grp * 16; e < t0; e += 64 * 16) {
        uint4 c0 = *(const uint4*)(codes + e);
        uint4 c1 = *(const uint4*)(codes + e + 4);
        uint4 c2 = *(const uint4*)(codes + e + 8);
        uint4 c3 = *(const uint4*)(codes + e + 12);
        __half2 w0 = GA(c0.x), w1 = GA(c0.y), w2 = GA(c0.z), w3 = GA(c0.w);
        __half2 w4 = GA(c1.x), w5 = GA(c1.y), w6 = GA(c1.z), w7 = GA(c1.w);
        __half2 w8 = GA(c2.x), w9 = GA(c2.y), wA = GA(c2.z), wB = GA(c2.w);
        __half2 wC = GA(c3.x), wD = GA(c3.y), wE = GA(c3.z), wF = GA(c3.w);
        ACC_EDGE(c0.x, w0); ACC_EDGE(c0.y, w1); ACC_EDGE(c0.z, w2); ACC_EDGE(c0.w, w3);
        ACC_EDGE(c1.x, w4); ACC_EDGE(c1.y, w5); ACC_EDGE(c1.z, w6); ACC_EDGE(c1.w, w7);
        ACC_EDGE(c2.x, w8); ACC_EDGE(c2.y, w9); ACC_EDGE(c2.z, wA); ACC_EDGE(c2.w, wB);
        ACC_EDGE(c3.x, wC); ACC_EDGE(c3.y, wD); ACC_EDGE(c3.z, wE); ACC_EDGE(c3.w, wF);
    }
    for (int e = t0 + grp; e < end; e += 64) {
        unsigned c = codes[e];
        __half2 w = GA(c);
        ACC_EDGE(c, w);
    }
#undef ACC_EDGE
#undef GA

    __syncthreads();
    const float bn0 = b_n[2 * sl], bn1 = b_n[2 * sl + 1];
    const float bs0 = b_s[2 * sl], bs1 = b_s[2 * sl + 1];
    const float wl0 = W_lin[2 * sl], wl1 = W_lin[2 * sl + 1];
    const float bl  = b_lin[0];
    for (int p = grp; p < 128; p += 64) {
        int node = b * 128 + p;
        if (node >= N) break;
        int rn = (2 * p) * LDSPAD, rs = rn + LDSPAD;
        float anx = (float)facc[rn + sl] * FXSI, any_ = (float)facc[rn + 16 + sl] * FXSI;
        float asx = (float)facc[rs + sl] * FXSI, asy  = (float)facc[rs + 16 + sl] * FXSI;
        float2 ns = __half22float2(xws[(size_t)(2 * node) * 16 + sl]);
        float2 ss = __half22float2(xws[(size_t)(2 * node + 1) * 16 + sl]);
        float dn  = rsqrtf((float)cnt[2 * node] + 1.0f);
        float dsv = rsqrtf((float)cnt[2 * node + 1] + 1.0f);
        float h0 = (anx + ns.x) * dn + bn0 + (asx + ss.x) * dsv + bs0;
        float h1 = (any_ + ns.y) * dn + bn1 + (asy + ss.y) * dsv + bs1;
        float pr = fmaxf(h0, 0.f) * wl0 + fmaxf(h1, 0.f) * wl1;
#pragma unroll
        for (int off = 8; off > 0; off >>= 1) pr += __shfl_xor(pr, off, 16);
        if (sl == 0) out[node] = pr + bl;
    }
}

extern "C" void kernel_launch(void* const* d_in, const int* in_sizes, int n_in,
                              void* d_out, int out_size, void* d_ws, size_t ws_size,
                              hipStream_t stream) {
    const float* x     = (const float*)d_in[0];
    const int*   ei_n  = (const int*)d_in[1];
    const int*   ei_s  = (const int*)d_in[2];
    const float* W_n   = (const float*)d_in[3];
    const float* b_n   = (const float*)d_in[4];
    const float* W_s   = (const float*)d_in[5];
    const float* b_s   = (const float*)d_in[6];
    const float* W_lin = (const float*)d_in[7];
    const float* b_lin = (const float*)d_in[8];
    float* out = (float*)d_out;

    const int N  = in_sizes[0] / 64;   // 100000
    const int En = in_sizes[1] / 2;    // 3200000
    const int Es = in_sizes[2] / 2;    // 3200000
    const int M  = 2 * N;              // 200000 vnodes (vn = 2*node + type)
    const int nb = (M + BSZ - 1) / BSZ;            // 782 buckets

    // Workspace (~43 MB): goff[1024] | cnt[M] | codes[nb*CAP2] (16B aligned)
    // | xws[16*M half2]
    int* goff = (int*)d_ws;
    int* cnt  = goff + 1024;
    uintptr_t pc = (uintptr_t)(cnt + M);
    pc = (pc + 15) & ~(uintptr_t)15;
    unsigned int* codes = (unsigned int*)pc;
    __half2* xws = (__half2*)(codes + (size_t)nb * CAP2);

    hipMemsetAsync(goff, 0, (size_t)nb * sizeof(int), stream);

    place_kernel<<<dim3(SLICES, 2), 512, 0, stream>>>(ei_n, ei_s, goff, codes,
                                                      En, Es, nb);
    dcount_kernel<<<nb, 256, 0, stream>>>(codes, goff, cnt, M);
    xw_kernel<<<(N + 15) / 16, 256, 0, stream>>>(x, W_n, W_s, cnt, xws, N);
    gather_kernel<<<nb, 1024, 0, stream>>>(codes, goff, xws, cnt,
                                           b_n, b_s, W_lin, b_lin, out, N);
}